// Round 3
// baseline (679.071 us; speedup 1.0000x reference)
//
#include <hip/hip_runtime.h>
#include <hip/hip_bf16.h>
#include <cstdint>
#include <cstddef>

#define C_CLS   100000
#define D_FEAT  512
#define B_ROWS  512

#define COSM 0.8775825618903728f
#define SINM 0.479425538604203f
#define TH_  (-0.8775825618903728f)
#define MM_  0.2397127693021015f   /* sin(0.5)*0.5 */

typedef __bf16 bf16x8 __attribute__((ext_vector_type(8)));
typedef __bf16 bf16x4 __attribute__((ext_vector_type(4)));
typedef float  f32x4  __attribute__((ext_vector_type(4)));

// ---------------- kernel 1: normalize x rows -> bf16, zero accumulators ----
__global__ void k_xnorm(const float* __restrict__ x, __bf16* __restrict__ xn,
                        float* __restrict__ row_sum, float* __restrict__ tlogit) {
    const int row  = blockIdx.x;          // 512 blocks
    const int lane = threadIdx.x;         // 64 threads
    const f32x4* p = (const f32x4*)(x + (size_t)row * D_FEAT);
    f32x4 a = p[lane];
    f32x4 b = p[lane + 64];
    float s = a[0]*a[0] + a[1]*a[1] + a[2]*a[2] + a[3]*a[3]
            + b[0]*b[0] + b[1]*b[1] + b[2]*b[2] + b[3]*b[3];
    #pragma unroll
    for (int m = 32; m >= 1; m >>= 1) s += __shfl_xor(s, m, 64);
    const float inv = 1.0f / fmaxf(sqrtf(s), 1e-12f);
    bf16x4 o0 = { (__bf16)(a[0]*inv), (__bf16)(a[1]*inv), (__bf16)(a[2]*inv), (__bf16)(a[3]*inv) };
    bf16x4 o1 = { (__bf16)(b[0]*inv), (__bf16)(b[1]*inv), (__bf16)(b[2]*inv), (__bf16)(b[3]*inv) };
    *(bf16x4*)(xn + (size_t)row * D_FEAT + lane * 4)       = o0;
    *(bf16x4*)(xn + (size_t)row * D_FEAT + 256 + lane * 4) = o1;
    if (lane == 0) { row_sum[row] = 0.0f; tlogit[row] = 0.0f; }
}

// ------- kernel 2: normalize weight rows -> bf16 (fused norm + cast) ------
__global__ void k_wnorm(const float* __restrict__ w, __bf16* __restrict__ wn) {
    const int row  = blockIdx.x * 4 + (threadIdx.x >> 6);   // 25000 blocks x 4 rows
    const int lane = threadIdx.x & 63;
    if (row >= C_CLS) return;
    const f32x4* p = (const f32x4*)(w + (size_t)row * D_FEAT);
    f32x4 a = p[lane];
    f32x4 b = p[lane + 64];
    float s = a[0]*a[0] + a[1]*a[1] + a[2]*a[2] + a[3]*a[3]
            + b[0]*b[0] + b[1]*b[1] + b[2]*b[2] + b[3]*b[3];
    #pragma unroll
    for (int m = 32; m >= 1; m >>= 1) s += __shfl_xor(s, m, 64);
    const float inv = 1.0f / fmaxf(sqrtf(s), 1e-12f);
    bf16x4 o0 = { (__bf16)(a[0]*inv), (__bf16)(a[1]*inv), (__bf16)(a[2]*inv), (__bf16)(a[3]*inv) };
    bf16x4 o1 = { (__bf16)(b[0]*inv), (__bf16)(b[1]*inv), (__bf16)(b[2]*inv), (__bf16)(b[3]*inv) };
    *(bf16x4*)(wn + (size_t)row * D_FEAT + lane * 4)       = o0;
    *(bf16x4*)(wn + (size_t)row * D_FEAT + 256 + lane * 4) = o1;
}

// ------- kernel 3: direct global->register MFMA GEMM + ArcFace epilogue ----
// No LDS staging: the 16x16x32 fragment IS "16 rows x 64B contiguous", so a
// wave's fragment load touches 16 full cache lines (4 lanes per 64B line).
// No barriers in the K-loop; depth-1 register prefetch pipelines latency.
__global__ __launch_bounds__(256, 2) void k_gemm(
        const __bf16* __restrict__ xn, const __bf16* __restrict__ wn,
        const int* __restrict__ y,
        float* __restrict__ row_sum, float* __restrict__ tlogit) {

    __shared__ int ys[128];

    const int tid = threadIdx.x;
    const int bm  = blockIdx.x & 3;
    const int bn  = blockIdx.x >> 2;

    if (tid < 128) ys[tid] = y[bm * 128 + tid];

    const int wave = tid >> 6;
    const int lane = tid & 63;
    const int wm   = wave >> 1;     // 0..1
    const int wn_  = wave & 1;      // 0..1
    const int quad = lane >> 4;     // 0..3
    const int l15  = lane & 15;

    // fragment base pointers: lane (quad,l15) of fragment i reads 16B at
    // row(i,l15)*512 + quad*8  (A: xn rows; B: wn rows, clamped at tail)
    const __bf16* ap[4];
    const __bf16* bp[4];
    #pragma unroll
    for (int i = 0; i < 4; ++i) {
        const int ar = bm * 128 + wm * 64 + i * 16 + l15;
        ap[i] = xn + (size_t)ar * D_FEAT + quad * 8;
        int br = bn * 128 + wn_ * 64 + i * 16 + l15;
        if (br > C_CLS - 1) br = C_CLS - 1;
        bp[i] = wn + (size_t)br * D_FEAT + quad * 8;
    }

    f32x4 acc[4][4];
    #pragma unroll
    for (int i = 0; i < 4; ++i)
        #pragma unroll
        for (int j = 0; j < 4; ++j) acc[i][j] = (f32x4){0.f, 0.f, 0.f, 0.f};

    bf16x8 a[2][4], b[2][4];
    #pragma unroll
    for (int i = 0; i < 4; ++i) {
        a[0][i] = *(const bf16x8*)(ap[i]);
        b[0][i] = *(const bf16x8*)(bp[i]);
    }

    #pragma unroll
    for (int kt = 0; kt < 16; ++kt) {
        const int cur = kt & 1, nxt = cur ^ 1;
        if (kt < 15) {
            const int ko = (kt + 1) * 32;
            #pragma unroll
            for (int i = 0; i < 4; ++i) {
                a[nxt][i] = *(const bf16x8*)(ap[i] + ko);
                b[nxt][i] = *(const bf16x8*)(bp[i] + ko);
            }
        }
        #pragma unroll
        for (int mi = 0; mi < 4; ++mi)
            #pragma unroll
            for (int ni = 0; ni < 4; ++ni)
                acc[mi][ni] = __builtin_amdgcn_mfma_f32_16x16x32_bf16(a[cur][mi], b[cur][ni], acc[mi][ni], 0, 0, 0);
    }

    __syncthreads();   // ys visibility for the epilogue

    // ---- epilogue: cos -> margin -> exp(logit-64) -> per-row partial sums ----
    #pragma unroll
    for (int mi = 0; mi < 4; ++mi) {
        float rs[4] = {0.f, 0.f, 0.f, 0.f};
        #pragma unroll
        for (int ni = 0; ni < 4; ++ni) {
            const int lcol = wn_ * 64 + ni * 16 + l15;
            const int gcol = bn * 128 + lcol;
            const bool colv = (gcol < C_CLS);
            #pragma unroll
            for (int reg = 0; reg < 4; ++reg) {
                const int lrow = wm * 64 + mi * 16 + quad * 4 + reg;
                const float cosv = acc[mi][ni][reg];
                const float sinv = sqrtf(fmaxf(1.0f - cosv * cosv, 0.0f));
                const float phi  = (cosv > TH_) ? (cosv * COSM - sinv * SINM) : (cosv - MM_);
                const bool ist   = colv && (gcol == ys[lrow]);
                const float logit = 64.0f * (ist ? phi : cosv);
                if (ist) tlogit[bm * 128 + lrow] = logit;
                rs[reg] += colv ? __expf(logit - 64.0f) : 0.0f;
            }
        }
        #pragma unroll
        for (int reg = 0; reg < 4; ++reg) {
            float v = rs[reg];
            v += __shfl_xor(v, 8, 64);
            v += __shfl_xor(v, 4, 64);
            v += __shfl_xor(v, 2, 64);
            v += __shfl_xor(v, 1, 64);
            if (l15 == 0) {
                const int lrow = wm * 64 + mi * 16 + quad * 4 + reg;
                atomicAdd(&row_sum[bm * 128 + lrow], v);
            }
        }
    }
}

// ---------------- kernel 4: finalize loss ---------------------------------
__global__ void k_final(const float* __restrict__ row_sum, const float* __restrict__ tlogit,
                        float* __restrict__ out) {
    const int t = threadIdx.x;     // 512 threads
    float v = logf(row_sum[t]) + 64.0f - tlogit[t];
    #pragma unroll
    for (int m = 32; m >= 1; m >>= 1) v += __shfl_xor(v, m, 64);
    __shared__ float partial[8];
    if ((t & 63) == 0) partial[t >> 6] = v;
    __syncthreads();
    if (t == 0) {
        float s = 0.f;
        #pragma unroll
        for (int i = 0; i < 8; ++i) s += partial[i];
        out[0] = s * (1.0f / 512.0f);
    }
}

extern "C" void kernel_launch(void* const* d_in, const int* in_sizes, int n_in,
                              void* d_out, int out_size, void* d_ws, size_t ws_size,
                              hipStream_t stream) {
    const float* x = (const float*)d_in[0];
    const int*   y = (const int*)d_in[1];
    const float* w = (const float*)d_in[2];

    char* ws = (char*)d_ws;
    __bf16* xn      = (__bf16*)ws;                                  // 524288 B
    __bf16* wnorm   = (__bf16*)(ws + 524288);                       // 102400000 B
    float*  row_sum = (float*)(ws + 524288 + 102400000);            // 2048 B
    float*  tlogit  = (float*)(ws + 524288 + 102400000 + 2048);     // 2048 B
    float*  out     = (float*)d_out;

    hipLaunchKernelGGL(k_xnorm, dim3(512), dim3(64), 0, stream, x, xn, row_sum, tlogit);
    hipLaunchKernelGGL(k_wnorm, dim3(25000), dim3(256), 0, stream, w, wnorm);
    hipLaunchKernelGGL(k_gemm, dim3(4 * 782), dim3(256), 0, stream, xn, wnorm, y, row_sum, tlogit);
    hipLaunchKernelGGL(k_final, dim3(1), dim3(512), 0, stream, row_sum, tlogit, out);
}

// Round 4
// 527.343 us; speedup vs baseline: 1.2877x; 1.2877x over previous
//
#include <hip/hip_runtime.h>
#include <hip/hip_bf16.h>
#include <cstdint>
#include <cstddef>

#define C_CLS   100000
#define D_FEAT  512
#define B_ROWS  512

#define COSM 0.8775825618903728f
#define SINM 0.479425538604203f
#define TH_  (-0.8775825618903728f)
#define MM_  0.2397127693021015f   /* sin(0.5)*0.5 */

typedef __bf16 bf16x8 __attribute__((ext_vector_type(8)));
typedef __bf16 bf16x4 __attribute__((ext_vector_type(4)));
typedef float  f32x4  __attribute__((ext_vector_type(4)));

typedef __attribute__((address_space(3))) void lds_void;
typedef const __attribute__((address_space(1))) void g_void;

__device__ __forceinline__ void async_copy16(const void* g, void* l) {
    __builtin_amdgcn_global_load_lds((g_void*)g, (lds_void*)l, 16, 0, 0);
}

// ---------------- kernel 1: normalize x rows -> bf16, zero accumulators ----
__global__ void k_xnorm(const float* __restrict__ x, __bf16* __restrict__ xn,
                        float* __restrict__ row_sum, float* __restrict__ tlogit) {
    const int row  = blockIdx.x;          // 512 blocks
    const int lane = threadIdx.x;         // 64 threads
    const f32x4* p = (const f32x4*)(x + (size_t)row * D_FEAT);
    f32x4 a = p[lane];
    f32x4 b = p[lane + 64];
    float s = a[0]*a[0] + a[1]*a[1] + a[2]*a[2] + a[3]*a[3]
            + b[0]*b[0] + b[1]*b[1] + b[2]*b[2] + b[3]*b[3];
    #pragma unroll
    for (int m = 32; m >= 1; m >>= 1) s += __shfl_xor(s, m, 64);
    const float inv = 1.0f / fmaxf(sqrtf(s), 1e-12f);
    bf16x4 o0 = { (__bf16)(a[0]*inv), (__bf16)(a[1]*inv), (__bf16)(a[2]*inv), (__bf16)(a[3]*inv) };
    bf16x4 o1 = { (__bf16)(b[0]*inv), (__bf16)(b[1]*inv), (__bf16)(b[2]*inv), (__bf16)(b[3]*inv) };
    *(bf16x4*)(xn + (size_t)row * D_FEAT + lane * 4)       = o0;
    *(bf16x4*)(xn + (size_t)row * D_FEAT + 256 + lane * 4) = o1;
    if (lane == 0) { row_sum[row] = 0.0f; tlogit[row] = 0.0f; }
}

// ------- kernel 2: normalize weight rows -> bf16 (fused norm + cast) ------
__global__ void k_wnorm(const float* __restrict__ w, __bf16* __restrict__ wn) {
    const int row  = blockIdx.x * 4 + (threadIdx.x >> 6);   // 25000 blocks x 4 rows
    const int lane = threadIdx.x & 63;
    if (row >= C_CLS) return;
    const f32x4* p = (const f32x4*)(w + (size_t)row * D_FEAT);
    f32x4 a = p[lane];
    f32x4 b = p[lane + 64];
    float s = a[0]*a[0] + a[1]*a[1] + a[2]*a[2] + a[3]*a[3]
            + b[0]*b[0] + b[1]*b[1] + b[2]*b[2] + b[3]*b[3];
    #pragma unroll
    for (int m = 32; m >= 1; m >>= 1) s += __shfl_xor(s, m, 64);
    const float inv = 1.0f / fmaxf(sqrtf(s), 1e-12f);
    bf16x4 o0 = { (__bf16)(a[0]*inv), (__bf16)(a[1]*inv), (__bf16)(a[2]*inv), (__bf16)(a[3]*inv) };
    bf16x4 o1 = { (__bf16)(b[0]*inv), (__bf16)(b[1]*inv), (__bf16)(b[2]*inv), (__bf16)(b[3]*inv) };
    *(bf16x4*)(wn + (size_t)row * D_FEAT + lane * 4)       = o0;
    *(bf16x4*)(wn + (size_t)row * D_FEAT + 256 + lane * 4) = o1;
}

// ---------------- kernel 3: MFMA GEMM + fused ArcFace epilogue ------------
// m97 structure: COALESCED global_load_lds staging (chunk c -> row=c>>2,
// k16=c&3: 4 lanes cover one row's contiguous 64B -> 16 mergeable lines per
// instruction), LDS tile [row][32] bf16 row-major contiguous.
__global__ __launch_bounds__(256, 3) void k_gemm(
        const __bf16* __restrict__ xn, const __bf16* __restrict__ wn,
        const int* __restrict__ y,
        float* __restrict__ row_sum, float* __restrict__ tlogit) {

    __shared__ __align__(16) __bf16 As[128 * 32];   // [row][32k] : 8 KB
    __shared__ __align__(16) __bf16 Bs[128 * 32];   // [row][32k] : 8 KB
    __shared__ int ys[128];

    const int tid = threadIdx.x;
    const int bm  = blockIdx.x & 3;
    const int bn  = blockIdx.x >> 2;

    if (tid < 128) ys[tid] = y[bm * 128 + tid];

    const int wave = tid >> 6;
    const int lane = tid & 63;
    const int wm   = wave >> 1;     // 0..1
    const int wn_  = wave & 1;      // 0..1
    const int quad = lane >> 4;     // 0..3
    const int l15  = lane & 15;

    // staging chunk decomposition (two chunks per thread per tile)
    const int c0 = tid, c1 = tid + 256;
    const int r0 = c0 >> 2, kc0 = (c0 & 3) * 8;
    const int r1 = c1 >> 2, kc1 = (c1 & 3) * 8;
    int bw0 = bn * 128 + r0; if (bw0 > C_CLS - 1) bw0 = C_CLS - 1;
    int bw1 = bn * 128 + r1; if (bw1 > C_CLS - 1) bw1 = C_CLS - 1;
    const __bf16* ga0 = xn + (size_t)(bm * 128 + r0) * D_FEAT + kc0;
    const __bf16* ga1 = xn + (size_t)(bm * 128 + r1) * D_FEAT + kc1;
    const __bf16* gb0 = wn + (size_t)bw0 * D_FEAT + kc0;
    const __bf16* gb1 = wn + (size_t)bw1 * D_FEAT + kc1;

    f32x4 acc[4][4];
    #pragma unroll
    for (int i = 0; i < 4; ++i)
        #pragma unroll
        for (int j = 0; j < 4; ++j) acc[i][j] = (f32x4){0.f, 0.f, 0.f, 0.f};

    for (int kt = 0; kt < 16; ++kt) {
        const int k0 = kt * 32;
        async_copy16(ga0 + k0, &As[(size_t)c0 * 8]);
        async_copy16(ga1 + k0, &As[(size_t)c1 * 8]);
        async_copy16(gb0 + k0, &Bs[(size_t)c0 * 8]);
        async_copy16(gb1 + k0, &Bs[(size_t)c1 * 8]);
        __syncthreads();

        bf16x8 af[4], bfr[4];
        #pragma unroll
        for (int mi = 0; mi < 4; ++mi) {
            const int r = wm * 64 + mi * 16 + l15;
            af[mi] = *(const bf16x8*)&As[(size_t)r * 32 + quad * 8];
        }
        #pragma unroll
        for (int ni = 0; ni < 4; ++ni) {
            const int r = wn_ * 64 + ni * 16 + l15;
            bfr[ni] = *(const bf16x8*)&Bs[(size_t)r * 32 + quad * 8];
        }
        #pragma unroll
        for (int mi = 0; mi < 4; ++mi)
            #pragma unroll
            for (int ni = 0; ni < 4; ++ni)
                acc[mi][ni] = __builtin_amdgcn_mfma_f32_16x16x32_bf16(af[mi], bfr[ni], acc[mi][ni], 0, 0, 0);
        __syncthreads();
    }

    // ---- epilogue: cos -> margin -> exp(logit-64) -> per-row partial sums ----
    #pragma unroll
    for (int mi = 0; mi < 4; ++mi) {
        float rs[4] = {0.f, 0.f, 0.f, 0.f};
        #pragma unroll
        for (int ni = 0; ni < 4; ++ni) {
            const int lcol = wn_ * 64 + ni * 16 + l15;
            const int gcol = bn * 128 + lcol;
            const bool colv = (gcol < C_CLS);
            #pragma unroll
            for (int reg = 0; reg < 4; ++reg) {
                const int lrow = wm * 64 + mi * 16 + quad * 4 + reg;
                const float cosv = acc[mi][ni][reg];
                const float sinv = sqrtf(fmaxf(1.0f - cosv * cosv, 0.0f));
                const float phi  = (cosv > TH_) ? (cosv * COSM - sinv * SINM) : (cosv - MM_);
                const bool ist   = colv && (gcol == ys[lrow]);
                const float logit = 64.0f * (ist ? phi : cosv);
                if (ist) tlogit[bm * 128 + lrow] = logit;
                rs[reg] += colv ? __expf(logit - 64.0f) : 0.0f;
            }
        }
        #pragma unroll
        for (int reg = 0; reg < 4; ++reg) {
            float v = rs[reg];
            v += __shfl_xor(v, 8, 64);
            v += __shfl_xor(v, 4, 64);
            v += __shfl_xor(v, 2, 64);
            v += __shfl_xor(v, 1, 64);
            if (l15 == 0) {
                const int lrow = wm * 64 + mi * 16 + quad * 4 + reg;
                atomicAdd(&row_sum[bm * 128 + lrow], v);
            }
        }
    }
}

// ---------------- kernel 4: finalize loss ---------------------------------
__global__ void k_final(const float* __restrict__ row_sum, const float* __restrict__ tlogit,
                        float* __restrict__ out) {
    const int t = threadIdx.x;     // 512 threads
    float v = logf(row_sum[t]) + 64.0f - tlogit[t];
    #pragma unroll
    for (int m = 32; m >= 1; m >>= 1) v += __shfl_xor(v, m, 64);
    __shared__ float partial[8];
    if ((t & 63) == 0) partial[t >> 6] = v;
    __syncthreads();
    if (t == 0) {
        float s = 0.f;
        #pragma unroll
        for (int i = 0; i < 8; ++i) s += partial[i];
        out[0] = s * (1.0f / 512.0f);
    }
}

extern "C" void kernel_launch(void* const* d_in, const int* in_sizes, int n_in,
                              void* d_out, int out_size, void* d_ws, size_t ws_size,
                              hipStream_t stream) {
    const float* x = (const float*)d_in[0];
    const int*   y = (const int*)d_in[1];
    const float* w = (const float*)d_in[2];

    char* ws = (char*)d_ws;
    __bf16* xn      = (__bf16*)ws;                                  // 524288 B
    __bf16* wnorm   = (__bf16*)(ws + 524288);                       // 102400000 B
    float*  row_sum = (float*)(ws + 524288 + 102400000);            // 2048 B
    float*  tlogit  = (float*)(ws + 524288 + 102400000 + 2048);     // 2048 B
    float*  out     = (float*)d_out;

    hipLaunchKernelGGL(k_xnorm, dim3(512), dim3(64), 0, stream, x, xn, row_sum, tlogit);
    hipLaunchKernelGGL(k_wnorm, dim3(25000), dim3(256), 0, stream, w, wnorm);
    hipLaunchKernelGGL(k_gemm, dim3(4 * 782), dim3(256), 0, stream, xn, wnorm, y, row_sum, tlogit);
    hipLaunchKernelGGL(k_final, dim3(1), dim3(512), 0, stream, row_sum, tlogit, out);
}

// Round 5
// 515.424 us; speedup vs baseline: 1.3175x; 1.0231x over previous
//
#include <hip/hip_runtime.h>
#include <hip/hip_bf16.h>
#include <cstdint>
#include <cstddef>

#define C_CLS   100000
#define D_FEAT  512
#define B_ROWS  512

#define COSM 0.8775825618903728f
#define SINM 0.479425538604203f
#define TH_  (-0.8775825618903728f)
#define MM_  0.2397127693021015f   /* sin(0.5)*0.5 */

typedef __bf16 bf16x8 __attribute__((ext_vector_type(8)));
typedef __bf16 bf16x4 __attribute__((ext_vector_type(4)));
typedef float  f32x4  __attribute__((ext_vector_type(4)));

// ---------------- kernel 1: normalize x rows -> bf16, zero accumulators ----
__global__ void k_xnorm(const float* __restrict__ x, __bf16* __restrict__ xn,
                        float* __restrict__ row_sum, float* __restrict__ tlogit) {
    const int row  = blockIdx.x;          // 512 blocks
    const int lane = threadIdx.x;         // 64 threads
    const f32x4* p = (const f32x4*)(x + (size_t)row * D_FEAT);
    f32x4 a = p[lane];
    f32x4 b = p[lane + 64];
    float s = a[0]*a[0] + a[1]*a[1] + a[2]*a[2] + a[3]*a[3]
            + b[0]*b[0] + b[1]*b[1] + b[2]*b[2] + b[3]*b[3];
    #pragma unroll
    for (int m = 32; m >= 1; m >>= 1) s += __shfl_xor(s, m, 64);
    const float inv = 1.0f / fmaxf(sqrtf(s), 1e-12f);
    bf16x4 o0 = { (__bf16)(a[0]*inv), (__bf16)(a[1]*inv), (__bf16)(a[2]*inv), (__bf16)(a[3]*inv) };
    bf16x4 o1 = { (__bf16)(b[0]*inv), (__bf16)(b[1]*inv), (__bf16)(b[2]*inv), (__bf16)(b[3]*inv) };
    *(bf16x4*)(xn + (size_t)row * D_FEAT + lane * 4)       = o0;
    *(bf16x4*)(xn + (size_t)row * D_FEAT + 256 + lane * 4) = o1;
    if (lane == 0) { row_sum[row] = 0.0f; tlogit[row] = 0.0f; }
}

// ------- kernel 2: normalize weight rows -> bf16 (fused norm + cast) ------
__global__ void k_wnorm(const float* __restrict__ w, __bf16* __restrict__ wn) {
    const int row  = blockIdx.x * 4 + (threadIdx.x >> 6);   // 25000 blocks x 4 rows
    const int lane = threadIdx.x & 63;
    if (row >= C_CLS) return;
    const f32x4* p = (const f32x4*)(w + (size_t)row * D_FEAT);
    f32x4 a = p[lane];
    f32x4 b = p[lane + 64];
    float s = a[0]*a[0] + a[1]*a[1] + a[2]*a[2] + a[3]*a[3]
            + b[0]*b[0] + b[1]*b[1] + b[2]*b[2] + b[3]*b[3];
    #pragma unroll
    for (int m = 32; m >= 1; m >>= 1) s += __shfl_xor(s, m, 64);
    const float inv = 1.0f / fmaxf(sqrtf(s), 1e-12f);
    bf16x4 o0 = { (__bf16)(a[0]*inv), (__bf16)(a[1]*inv), (__bf16)(a[2]*inv), (__bf16)(a[3]*inv) };
    bf16x4 o1 = { (__bf16)(b[0]*inv), (__bf16)(b[1]*inv), (__bf16)(b[2]*inv), (__bf16)(b[3]*inv) };
    *(bf16x4*)(wn + (size_t)row * D_FEAT + lane * 4)       = o0;
    *(bf16x4*)(wn + (size_t)row * D_FEAT + 256 + lane * 4) = o1;
}

// ---------------- kernel 3: MFMA GEMM + fused ArcFace epilogue ------------
// Classic pipeline (AITER-style): global_load_dwordx4 -> VGPR prefetch ->
// ds_write_b128, double-buffered LDS, one barrier per K-iter. NO
// global_load_lds (its per-lane TA requests cap staging at ~5.6 B/cyc/CU —
// the measured R1/R2/R4 plateau). XOR-swizzled LDS: chunk (row,kq) stored at
// kq ^ (row&3) ^ ((row>>2)&3); both ds_write and fragment ds_read <=2-way.
__global__ __launch_bounds__(256, 3) void k_gemm(
        const __bf16* __restrict__ xn, const __bf16* __restrict__ wn,
        const int* __restrict__ y,
        float* __restrict__ row_sum, float* __restrict__ tlogit) {

    __shared__ __align__(16) __bf16 As[2][128 * 32];   // 8 KB each
    __shared__ __align__(16) __bf16 Bs[2][128 * 32];
    __shared__ int ys[128];

    const int tid = threadIdx.x;
    const int bm  = blockIdx.x & 3;
    const int bn  = blockIdx.x >> 2;

    if (tid < 128) ys[tid] = y[bm * 128 + tid];

    const int wave = tid >> 6;
    const int lane = tid & 63;
    const int wm   = wave >> 1;     // 0..1
    const int wn_  = wave & 1;      // 0..1
    const int quad = lane >> 4;     // 0..3
    const int l15  = lane & 15;

    // staging: chunks c0=tid, c1=tid+256 of 512; chunk c -> row=c>>2, kq=c&3
    // global: 4 consecutive lanes cover one row's contiguous 64B (coalesced).
    const int r0 = tid >> 2, q0 = tid & 3;
    const int r1 = r0 + 64,  q1 = q0;          // c1 = tid+256 -> row+64, same kq
    int bw0 = bn * 128 + r0; if (bw0 > C_CLS - 1) bw0 = C_CLS - 1;
    int bw1 = bn * 128 + r1; if (bw1 > C_CLS - 1) bw1 = C_CLS - 1;
    const __bf16* gA0 = xn + (size_t)(bm * 128 + r0) * D_FEAT + q0 * 8;
    const __bf16* gA1 = xn + (size_t)(bm * 128 + r1) * D_FEAT + q1 * 8;
    const __bf16* gB0 = wn + (size_t)bw0 * D_FEAT + q0 * 8;
    const __bf16* gB1 = wn + (size_t)bw1 * D_FEAT + q1 * 8;
    // LDS elem offsets (swizzled)
    const int wo0 = (r0 * 4 + (q0 ^ (r0 & 3) ^ ((r0 >> 2) & 3))) * 8;
    const int wo1 = (r1 * 4 + (q1 ^ (r1 & 3) ^ ((r1 >> 2) & 3))) * 8;
    // fragment read offsets: row r = base + l15, chunk kq = quad
    const int fsw = (quad ^ (l15 & 3) ^ ((l15 >> 2) & 3)) * 8;

    f32x4 acc[4][4];
    #pragma unroll
    for (int i = 0; i < 4; ++i)
        #pragma unroll
        for (int j = 0; j < 4; ++j) acc[i][j] = (f32x4){0.f, 0.f, 0.f, 0.f};

    // prologue: k-tile 0 -> regs -> LDS[0]
    bf16x8 sa0 = *(const bf16x8*)gA0, sa1 = *(const bf16x8*)gA1;
    bf16x8 sb0 = *(const bf16x8*)gB0, sb1 = *(const bf16x8*)gB1;
    *(bf16x8*)&As[0][wo0] = sa0;  *(bf16x8*)&As[0][wo1] = sa1;
    *(bf16x8*)&Bs[0][wo0] = sb0;  *(bf16x8*)&Bs[0][wo1] = sb1;
    __syncthreads();

    #pragma unroll
    for (int kt = 0; kt < 16; ++kt) {
        const int cur = kt & 1, nxt = cur ^ 1;
        if (kt < 15) {                       // prefetch k+1 into regs (in flight during compute)
            const int ko = (kt + 1) * 32;
            sa0 = *(const bf16x8*)(gA0 + ko);  sa1 = *(const bf16x8*)(gA1 + ko);
            sb0 = *(const bf16x8*)(gB0 + ko);  sb1 = *(const bf16x8*)(gB1 + ko);
        }
        bf16x8 af[4], bfr[4];
        #pragma unroll
        for (int mi = 0; mi < 4; ++mi) {
            const int r = wm * 64 + mi * 16 + l15;
            af[mi] = *(const bf16x8*)&As[cur][r * 32 + fsw];
        }
        #pragma unroll
        for (int ni = 0; ni < 4; ++ni) {
            const int r = wn_ * 64 + ni * 16 + l15;
            bfr[ni] = *(const bf16x8*)&Bs[cur][r * 32 + fsw];
        }
        #pragma unroll
        for (int mi = 0; mi < 4; ++mi)
            #pragma unroll
            for (int ni = 0; ni < 4; ++ni)
                acc[mi][ni] = __builtin_amdgcn_mfma_f32_16x16x32_bf16(af[mi], bfr[ni], acc[mi][ni], 0, 0, 0);
        if (kt < 15) {
            *(bf16x8*)&As[nxt][wo0] = sa0;  *(bf16x8*)&As[nxt][wo1] = sa1;
            *(bf16x8*)&Bs[nxt][wo0] = sb0;  *(bf16x8*)&Bs[nxt][wo1] = sb1;
        }
        __syncthreads();
    }

    // ---- epilogue: cos -> margin -> exp(logit-64) -> per-row partial sums ----
    #pragma unroll
    for (int mi = 0; mi < 4; ++mi) {
        float rs[4] = {0.f, 0.f, 0.f, 0.f};
        #pragma unroll
        for (int ni = 0; ni < 4; ++ni) {
            const int lcol = wn_ * 64 + ni * 16 + l15;
            const int gcol = bn * 128 + lcol;
            const bool colv = (gcol < C_CLS);
            #pragma unroll
            for (int reg = 0; reg < 4; ++reg) {
                const int lrow = wm * 64 + mi * 16 + quad * 4 + reg;
                const float cosv = acc[mi][ni][reg];
                const float sinv = sqrtf(fmaxf(1.0f - cosv * cosv, 0.0f));
                const float phi  = (cosv > TH_) ? (cosv * COSM - sinv * SINM) : (cosv - MM_);
                const bool ist   = colv && (gcol == ys[lrow]);
                const float logit = 64.0f * (ist ? phi : cosv);
                if (ist) tlogit[bm * 128 + lrow] = logit;
                rs[reg] += colv ? __expf(logit - 64.0f) : 0.0f;
            }
        }
        #pragma unroll
        for (int reg = 0; reg < 4; ++reg) {
            float v = rs[reg];
            v += __shfl_xor(v, 8, 64);
            v += __shfl_xor(v, 4, 64);
            v += __shfl_xor(v, 2, 64);
            v += __shfl_xor(v, 1, 64);
            if (l15 == 0) {
                const int lrow = wm * 64 + mi * 16 + quad * 4 + reg;
                atomicAdd(&row_sum[bm * 128 + lrow], v);
            }
        }
    }
}

// ---------------- kernel 4: finalize loss ---------------------------------
__global__ void k_final(const float* __restrict__ row_sum, const float* __restrict__ tlogit,
                        float* __restrict__ out) {
    const int t = threadIdx.x;     // 512 threads
    float v = logf(row_sum[t]) + 64.0f - tlogit[t];
    #pragma unroll
    for (int m = 32; m >= 1; m >>= 1) v += __shfl_xor(v, m, 64);
    __shared__ float partial[8];
    if ((t & 63) == 0) partial[t >> 6] = v;
    __syncthreads();
    if (t == 0) {
        float s = 0.f;
        #pragma unroll
        for (int i = 0; i < 8; ++i) s += partial[i];
        out[0] = s * (1.0f / 512.0f);
    }
}

extern "C" void kernel_launch(void* const* d_in, const int* in_sizes, int n_in,
                              void* d_out, int out_size, void* d_ws, size_t ws_size,
                              hipStream_t stream) {
    const float* x = (const float*)d_in[0];
    const int*   y = (const int*)d_in[1];
    const float* w = (const float*)d_in[2];

    char* ws = (char*)d_ws;
    __bf16* xn      = (__bf16*)ws;                                  // 524288 B
    __bf16* wnorm   = (__bf16*)(ws + 524288);                       // 102400000 B
    float*  row_sum = (float*)(ws + 524288 + 102400000);            // 2048 B
    float*  tlogit  = (float*)(ws + 524288 + 102400000 + 2048);     // 2048 B
    float*  out     = (float*)d_out;

    hipLaunchKernelGGL(k_xnorm, dim3(512), dim3(64), 0, stream, x, xn, row_sum, tlogit);
    hipLaunchKernelGGL(k_wnorm, dim3(25000), dim3(256), 0, stream, w, wnorm);
    hipLaunchKernelGGL(k_gemm, dim3(4 * 782), dim3(256), 0, stream, xn, wnorm, y, row_sum, tlogit);
    hipLaunchKernelGGL(k_final, dim3(1), dim3(512), 0, stream, row_sum, tlogit, out);
}